// Round 13
// baseline (1721.178 us; speedup 1.0000x reference)
//
#include <hip/hip_runtime.h>
#include <math.h>

#define KNB 24

typedef float v2f __attribute__((ext_vector_type(2)));

// ---------------------------------------------------------------- tiled transpose
// x [B,C,N] -> feats [B,N,C]; 32x32 LDS tiles, both sides coalesced (kills 8x write amp)
__global__ __launch_bounds__(256) void k_transpose(const float* __restrict__ x,
                                                   float* __restrict__ feats,
                                                   int C, int N) {
    __shared__ float tile[32][33];
    int b = blockIdx.z;
    int n0 = blockIdx.x * 32, c0 = blockIdx.y * 32;
    int tx = threadIdx.x, ty = threadIdx.y;      // block (32,8)
#pragma unroll
    for (int k = 0; k < 4; ++k) {
        int c = c0 + ty + k * 8, n = n0 + tx;
        if (c < C && n < N) tile[ty + k * 8][tx] = x[((size_t)b * C + c) * N + n];
    }
    __syncthreads();
#pragma unroll
    for (int k = 0; k < 4; ++k) {
        int n = n0 + ty + k * 8, c = c0 + tx;
        if (c < C && n < N) feats[((size_t)b * N + n) * C + c] = tile[tx][ty + k * 8];
    }
}

// ---------------------------------------------------------------- DPP reduce helpers
template<int CTRL>
__device__ __forceinline__ float dppmax(float v) {
    int t = __builtin_amdgcn_update_dpp(0, __float_as_int(v), CTRL, 0xf, 0xf, true);
    return fmaxf(v, __int_as_float(t));
}
template<int CTRL>
__device__ __forceinline__ unsigned dppmaxu(unsigned v) {
    unsigned t = (unsigned)__builtin_amdgcn_update_dpp(0, (int)v, CTRL, 0xf, 0xf, true);
    return v > t ? v : t;
}

// ---------------------------------------------------------------- FPS (frozen: floor of 8 variants)
template<int NPT, int NWAVE>   // NPT even
__global__ __launch_bounds__(64 * NWAVE) void k_fps_t(const float* __restrict__ xyz,
                                                      int* __restrict__ fi,
                                                      int N, int M) {
#pragma clang fp contract(off)
    const int NP2 = NPT / 2;
    const int b = blockIdx.x;
    const int tid = threadIdx.x;
    const int lane = tid & 63;
    const int wid = tid >> 6;
    extern __shared__ char smc[];
    unsigned long long* keys = (unsigned long long*)smc;   // [2][NWAVE] parity dbuf
    int* fi_lds = (int*)(smc + 2 * NWAVE * 8);             // [M]
    size_t poff = ((size_t)(2 * NWAVE * 8) + (size_t)M * 4 + 15) & ~(size_t)15;
    float4* pts = (float4*)(smc + poff);                   // [N] packed xyz

    const float* p = xyz + (size_t)b * N * 3;
    for (int i = tid; i < N; i += 64 * NWAVE)
        pts[i] = make_float4(p[i*3], p[i*3+1], p[i*3+2], 0.0f);
    __syncthreads();

    const int base = tid * NPT;
    v2f rx[NP2], ry[NP2], rz[NP2], dist[NP2];
#pragma unroll
    for (int j = 0; j < NP2; ++j) {
        float4 a = pts[base + 2*j];
        float4 c = pts[base + 2*j + 1];
        rx[j] = (v2f){a.x, c.x}; ry[j] = (v2f){a.y, c.y}; rz[j] = (v2f){a.z, c.z};
        dist[j] = (v2f){1e10f, 1e10f};
    }

    int far = 0;
    float4 cpt = pts[0];
    float cx = cpt.x, cy = cpt.y, cz = cpt.z;
    for (int it = 0; it < M; ++it) {
        if (tid == 0) fi_lds[it] = far;               // record carry BEFORE update
        v2f cx2 = (v2f){cx, cx}, cy2 = (v2f){cy, cy}, cz2 = (v2f){cz, cz};
        v2f bv2 = (v2f){-1.0f, -1.0f};
#pragma unroll
        for (int j = 0; j < NP2; ++j) {
            v2f dx = rx[j] - cx2, dy = ry[j] - cy2, dz = rz[j] - cz2;
            v2f d = (dx*dx + dy*dy) + dz*dz;          // ((d0+d1)+d2) per elem, no fma
            v2f dd = __builtin_elementwise_min(dist[j], d);
            dist[j] = dd;
            bv2 = __builtin_elementwise_max(bv2, dd);
        }
        float bv = fmaxf(bv2.x, bv2.y);
        int bi = 0;
#pragma unroll
        for (int j = NP2 - 1; j >= 0; --j) {
            if (dist[j].y == bv) bi = base + 2*j + 1;
            if (dist[j].x == bv) bi = base + 2*j;
        }
        float r = bv;
        r = dppmax<0x111>(r); r = dppmax<0x112>(r);
        r = dppmax<0x114>(r); r = dppmax<0x118>(r);
        r = dppmax<0x142>(r); r = dppmax<0x143>(r);
        float wmax = __int_as_float(__builtin_amdgcn_readlane(__float_as_int(r), 63));
        unsigned long long mask = __ballot(bv == wmax);
        int src = __builtin_ctzll(mask);
        int wbi = __builtin_amdgcn_readlane(bi, src);
        unsigned long long key =
            ((unsigned long long)__float_as_uint(wmax) << 32) | (unsigned)(~wbi);
        if (lane == 0) keys[(it & 1) * NWAVE + wid] = key;
        __syncthreads();
        unsigned long long k0 = keys[(it & 1) * NWAVE + 0];
#pragma unroll
        for (int w = 1; w < NWAVE; ++w) {
            unsigned long long kw = keys[(it & 1) * NWAVE + w];
            if (kw > k0) k0 = kw;
        }
        far = (int)(~(unsigned)k0);
        float4 c = pts[far];                           // single ds_read_b128
        cx = c.x; cy = c.y; cz = c.z;
    }
    __syncthreads();
    for (int i = tid; i < M; i += 64 * NWAVE) fi[b * M + i] = fi_lds[i];
}

// ---------------------------------------------------------------- kNN + gather + fused std partials
template<int NPT>
__global__ __launch_bounds__(256) void k_knn_t(const float* __restrict__ xyz,
                                               const float* __restrict__ feats,
                                               const int* __restrict__ fi,
                                               float* __restrict__ lc_xyz,
                                               float* __restrict__ lc_x,
                                               int* __restrict__ ki,
                                               double* __restrict__ part,
                                               int B, int N, int G, int C, int identity) {
#pragma clang fp contract(off)
    int bg = blockIdx.x; int b = bg / G; int g = bg % G;
    int idx = identity ? g : fi[bg];
    const int tid = threadIdx.x;
    const int lane = tid & 63;
    const int wid = tid >> 6;
    __shared__ unsigned long long keys[2][4];   // parity dbuf
    __shared__ int kis[KNB];
    __shared__ float cfeat[144];                // center feats cache (C <= 144)
    const float* p = xyz + (size_t)b * N * 3;
    float cx = p[idx*3], cy = p[idx*3+1], cz = p[idx*3+2];
    if (tid < 3) lc_xyz[(size_t)bg * 3 + tid] = p[idx*3 + tid];
    for (int c = tid; c < C; c += 256) {
        float v = feats[((size_t)b * N + idx) * C + c];
        lc_x[(size_t)bg * C + c] = v;
        cfeat[c] = v;
    }
    float cc = (cx*cx + cy*cy) + cz*cz;
    const int base = tid * NPT;
    float dist[NPT];
#pragma unroll
    for (int j = 0; j < NPT; ++j) {
        float x0 = p[(base+j)*3], x1 = p[(base+j)*3+1], x2 = p[(base+j)*3+2];
        float xx = (x0*x0 + x1*x1) + x2*x2;
        float dt = (cx*x0 + cy*x1) + cz*x2;
        dist[j] = (cc - 2.0f*dt) + xx;        // (cc - 2dot) + xx, matches ref assoc
    }
    for (int kk = 0; kk < KNB; ++kk) {
        float bv = 1e30f;
#pragma unroll
        for (int j = 0; j < NPT; ++j) bv = fminf(bv, dist[j]);
        int lj = 0;
#pragma unroll
        for (int j = NPT - 1; j >= 0; --j) if (dist[j] == bv) lj = j;  // first-min
        unsigned ub = ~__float_as_uint(bv);
        unsigned r = ub;
        r = dppmaxu<0x111>(r); r = dppmaxu<0x112>(r);
        r = dppmaxu<0x114>(r); r = dppmaxu<0x118>(r);
        r = dppmaxu<0x142>(r); r = dppmaxu<0x143>(r);
        unsigned uwin = (unsigned)__builtin_amdgcn_readlane((int)r, 63);
        unsigned long long mask = __ballot(ub == uwin);
        int src = __builtin_ctzll(mask);
        int gi = __builtin_amdgcn_readlane(base + lj, src);
        unsigned long long key = ((unsigned long long)uwin << 32) | (unsigned)(~gi);
        if (lane == 0) keys[kk & 1][wid] = key;
        __syncthreads();
        unsigned long long k0 = keys[kk & 1][0];
#pragma unroll
        for (int w = 1; w < 4; ++w) {
            unsigned long long kw = keys[kk & 1][w];
            if (kw > k0) k0 = kw;
        }
        int win = (int)(~(unsigned)k0);
        if (tid == 0) kis[kk] = win;
        if (win >= base && win < base + NPT) {
            int wj = win - base;
#pragma unroll
            for (int j = 0; j < NPT; ++j) if (j == wj) dist[j] = 1e30f;
        }
    }
    __syncthreads();
    if (tid < KNB) ki[(size_t)bg * KNB + tid] = kis[tid];
    // fused std partial sums
    double s = 0.0, s2 = 0.0, s3 = 0.0, s4 = 0.0;
    for (int i = tid; i < KNB * C; i += 256) {
        int k = i / C, c = i - k * C;
        float d = feats[((size_t)b * N + kis[k]) * C + c] - cfeat[c];
        s += (double)d; s2 += (double)d * (double)d;
    }
    if (tid < KNB * 3) {
        int k = tid / 3, c = tid - k * 3;
        float ctr = (c == 0) ? cx : ((c == 1) ? cy : cz);
        float d = p[kis[k] * 3 + c] - ctr;
        s3 += (double)d; s4 += (double)d * (double)d;
    }
    for (int off = 32; off > 0; off >>= 1) {
        s += __shfl_down(s, off); s2 += __shfl_down(s2, off);
        s3 += __shfl_down(s3, off); s4 += __shfl_down(s4, off);
    }
    __shared__ double sw[4][4];
    if ((tid & 63) == 0) {
        sw[wid][0] = s; sw[wid][1] = s2; sw[wid][2] = s3; sw[wid][3] = s4;
    }
    __syncthreads();
    if (tid == 0) {
        double t0 = 0.0, t1 = 0.0, t2 = 0.0, t3 = 0.0;
        for (int w = 0; w < 4; ++w) {
            t0 += sw[w][0]; t1 += sw[w][1]; t2 += sw[w][2]; t3 += sw[w][3];
        }
        double* q = part + (size_t)bg * 4;
        q[0] = t0; q[1] = t1; q[2] = t2; q[3] = t3;
    }
}

// ---------------------------------------------------------------- per-block partials -> acc[0..3]
__global__ __launch_bounds__(1024) void k_reduce(const double* __restrict__ part,
                                                 double* __restrict__ acc, int n) {
    double s0 = 0.0, s1 = 0.0, s2 = 0.0, s3 = 0.0;
    for (int i = threadIdx.x; i < n; i += 1024) {
        const double* q = part + (size_t)i * 4;
        s0 += q[0]; s1 += q[1]; s2 += q[2]; s3 += q[3];
    }
    for (int off = 32; off > 0; off >>= 1) {
        s0 += __shfl_down(s0, off); s1 += __shfl_down(s1, off);
        s2 += __shfl_down(s2, off); s3 += __shfl_down(s3, off);
    }
    __shared__ double sw[16][4];
    int wid = threadIdx.x >> 6;
    if ((threadIdx.x & 63) == 0) {
        sw[wid][0] = s0; sw[wid][1] = s1; sw[wid][2] = s2; sw[wid][3] = s3;
    }
    __syncthreads();
    if (threadIdx.x == 0) {
        double t0 = 0.0, t1 = 0.0, t2 = 0.0, t3 = 0.0;
        for (int w = 0; w < 16; ++w) {
            t0 += sw[w][0]; t1 += sw[w][1]; t2 += sw[w][2]; t3 += sw[w][3];
        }
        acc[0] = t0; acc[1] = t1; acc[2] = t2; acc[3] = t3;
    }
}

// ---------------------------------------------------------------- LGA feature + pool (one wg per (b,g))
// R13: pooled written [B,G,Cout] -> 288 consecutive floats per block (coalesced,
// kills the 8x partial-line write amplification seen in R12's WRITE_SIZE).
__global__ __launch_bounds__(256) void k_feature(
    const float* __restrict__ xyz, const float* __restrict__ feats,
    const float* __restrict__ lc_xyz, const float* __restrict__ lc_x,
    const int* __restrict__ ki, const float* __restrict__ Bmat,
    const double* __restrict__ accp, float* __restrict__ pooled,
    int B, int N, int G, int C, double nx, double nz)
{
    int bg = blockIdx.x; int b = bg / G; int g = bg % G;
    int tid = threadIdx.x;
    int C2 = C >> 1;
    int Cout = 2 * C;
    int F = C / 3;                         // tr_embed F = (2C)/(2*3)
    extern __shared__ float sm[];
    float* t7    = sm;                     // [24][7]
    float* sxyzn = t7 + KNB * 7;           // [24][3]
    int*   kidx  = (int*)(sxyzn + KNB * 3);// [24]
    float* semb  = (float*)(kidx + KNB);   // [24][C]
    float* sfeat = semb + KNB * C;         // [24][C]

    double a0 = accp[0], a1 = accp[1], a2 = accp[2], a3 = accp[3];
    double vx = (a1 - a0 * a0 / nx) / (nx - 1.0);
    float invx = 1.0f / (sqrtf((float)vx) + 1e-5f);
    double vz = (a3 - a2 * a2 / nz) / (nz - 1.0);
    float invz = 1.0f / (sqrtf((float)vz) + 1e-5f);

    float l0 = lc_xyz[(size_t)bg*3], l1 = lc_xyz[(size_t)bg*3+1], l2 = lc_xyz[(size_t)bg*3+2];

    if (tid < KNB) {
        int idx = ki[(size_t)bg * KNB + tid];
        kidx[tid] = idx;
        const float* q = xyz + ((size_t)b * N + idx) * 3;
        float a0f = (q[0]-l0)*invz, a1f = (q[1]-l1)*invz, a2f = (q[2]-l2)*invz;
        float c0 = a1f*l2 - a2f*l1;        // cross(normed knn_xyz, raw lc_xyz)
        float c1 = a2f*l0 - a0f*l2;
        float c2 = a0f*l1 - a1f*l0;
        float dt = (a0f*l0 + a1f*l1) + a2f*l2;
        float* tp = t7 + tid * 7;
        tp[0]=a0f; tp[1]=a1f; tp[2]=a2f; tp[3]=c0; tp[4]=c1; tp[5]=c2; tp[6]=dt;
        sxyzn[tid*3]=a0f; sxyzn[tid*3+1]=a1f; sxyzn[tid*3+2]=a2f;
    }
    __syncthreads();
    // stage knn feature rows (coalesced row loads)
    for (int i = tid; i < KNB * C; i += blockDim.x) {
        int k = i / C, c = i - k * C;
        sfeat[i] = feats[((size_t)b * N + kidx[k]) * C + c];
    }
    const float TWO_PI = 6.2831854820251465f;
    for (int i = tid; i < KNB * C2; i += blockDim.x) {
        int k = i / C2, m2 = i % C2;
        const float* tp = t7 + k * 7;
        float s = 0.0f;
        for (int j = 0; j < 7; ++j) s += tp[j] * Bmat[j * C2 + m2];
        float pr = TWO_PI * s;
        float sn, cs;
        __sincosf(pr, &sn, &cs);
        float sn2 = sn*sn, cs2 = cs*cs;
        semb[k*C + m2]      = sn2*sn2*sn;
        semb[k*C + C2 + m2] = cs2*cs2*cs;
    }
    __syncthreads();
    for (int m = tid; m < Cout; m += blockDim.x) {
        int c3 = m / (2 * F);
        int r  = m % (2 * F);
        int f  = r >> 1;
        int trig = r & 1;
        float de = __powf(100.0f, (float)f / (float)F);
        float rde = 1000.0f / de;          // hoisted: k-loop uses mul, not div
        float lv = (c3 == 0) ? l0 : ((c3 == 1) ? l1 : l2);
        float a2v = lv * rde;
        float pe2 = trig ? __cosf(a2v) : __sinf(a2v);
        float lfm = (m < C) ? lc_x[(size_t)bg * C + m] : 0.0f;
        float acc = 0.0f;
        for (int k = 0; k < KNB; ++k) {
            float v;
            if (m < C) {
                v = (sfeat[k * C + m] - lfm) * invx;
            } else {
                v = semb[k * C + (m - C)];
            }
            float a1v = sxyzn[k*3 + c3] * rde;
            float pe1 = trig ? __cosf(a1v) : __sinf(a1v);
            float pe = pe1 + pe2;
            acc += (v + pe) * pe;
        }
        float mean = acc / 24.0f;
        pooled[((size_t)bg) * Cout + m] = 2.0f * mean;   // [B,G,Cout] coalesced
    }
}

// ---------------------------------------------------------------- BN stats partials (coalesced reads)
// pooled [rows, Cout]; thread t owns channels t and t+256; NB blocks x row-chunks.
__global__ __launch_bounds__(256) void k_bnstat(const float* __restrict__ pooled,
                                                double* __restrict__ bnpart,
                                                int rows, int Cout, int rowsPerBlk) {
    int blk = blockIdx.x;
    int r0 = blk * rowsPerBlk;
    int r1 = r0 + rowsPerBlk; if (r1 > rows) r1 = rows;
    int t = threadIdx.x;
    double s0 = 0.0, q0 = 0.0, s1 = 0.0, q1 = 0.0;
    for (int r = r0; r < r1; ++r) {
        const float* row = pooled + (size_t)r * Cout;
        if (t < Cout)       { float v = row[t];       s0 += (double)v; q0 += (double)v * v; }
        if (t + 256 < Cout) { float v = row[t + 256]; s1 += (double)v; q1 += (double)v * v; }
    }
    double* p = bnpart + (size_t)blk * Cout * 2;
    if (t < Cout)       { p[t * 2] = s0;           p[t * 2 + 1] = q0; }
    if (t + 256 < Cout) { p[(t + 256) * 2] = s1;   p[(t + 256) * 2 + 1] = q1; }
}

// per-channel finalize: sum NB partials -> mean/var (biased) -> stats[2m],[2m+1]
__global__ __launch_bounds__(512) void k_bnfin(const double* __restrict__ bnpart,
                                               float* __restrict__ stats,
                                               int NB, int Cout, double n) {
    int m = threadIdx.x;
    if (m >= Cout) return;
    double s = 0.0, q = 0.0;
    for (int b2 = 0; b2 < NB; ++b2) {
        const double* p = bnpart + ((size_t)b2 * Cout + m) * 2;
        s += p[0]; q += p[1];
    }
    double mean = s / n;
    double var = q / n - mean * mean;
    stats[2 * m] = (float)mean; stats[2 * m + 1] = (float)var;
}

// elementwise BN+GELU, same layout in/out ([B,G,Cout] -> [B,G,Cout]): fully coalesced
__global__ void k_bnapply(const float* __restrict__ pooled, const float* __restrict__ stats,
                          const float* __restrict__ gamma, const float* __restrict__ beta,
                          float* __restrict__ outp, int tot, int Cout) {
    int i = blockIdx.x * 256 + threadIdx.x;
    if (i >= tot) return;
    int m = i % Cout;
    float v = pooled[i];
    float mean = stats[2*m], var = stats[2*m+1];
    float y = (v - mean) / sqrtf(var + 1e-5f) * gamma[m] + beta[m];
    outp[i] = 0.5f * y * (1.0f + erff(y / 1.4142135381698608f));
}

// BN+GELU + 32x32 tiled transpose: pooled [B,G,Cout] -> out [B,Cout,G]; both sides coalesced
__global__ __launch_bounds__(256) void k_bnapply_t(const float* __restrict__ pooled,
                                                   const float* __restrict__ stats,
                                                   const float* __restrict__ gamma,
                                                   const float* __restrict__ beta,
                                                   float* __restrict__ outp,
                                                   int G, int Cout) {
    __shared__ float tile[32][33];
    int b = blockIdx.z;
    int g0 = blockIdx.x * 32, m0 = blockIdx.y * 32;
    int tx = threadIdx.x, ty = threadIdx.y;      // block (32,8)
#pragma unroll
    for (int k = 0; k < 4; ++k) {
        int g = g0 + ty + k * 8, m = m0 + tx;
        if (g < G && m < Cout) {
            float v = pooled[((size_t)b * G + g) * Cout + m];
            float mean = stats[2*m], var = stats[2*m+1];
            float y = (v - mean) / sqrtf(var + 1e-5f) * gamma[m] + beta[m];
            tile[ty + k * 8][tx] = 0.5f * y * (1.0f + erff(y / 1.4142135381698608f));
        }
    }
    __syncthreads();
#pragma unroll
    for (int k = 0; k < 4; ++k) {
        int m = m0 + ty + k * 8, g = g0 + tx;
        if (g < G && m < Cout) outp[((size_t)b * Cout + m) * G + g] = tile[tx][ty + k * 8];
    }
}

// ---------------------------------------------------------------- launch
extern "C" void kernel_launch(void* const* d_in, const int* in_sizes, int n_in,
                              void* d_out, int out_size, void* d_ws, size_t ws_size,
                              hipStream_t stream) {
    const int B = 4, N1 = 4096, C0 = 72, G1 = 2048, Co1 = 144;
    const int N2 = 2048, C1 = 144, G2 = 1024, Co2 = 288;
    const int NB = 64;   // bnstat blocks

    const float* xyz = (const float*)d_in[0];
    const float* x0  = (const float*)d_in[1];
    const float* B0  = (const float*)d_in[2];
    const float* B1  = (const float*)d_in[3];
    const float* g0  = (const float*)d_in[4];
    const float* be0 = (const float*)d_in[5];
    const float* g1  = (const float*)d_in[6];
    const float* be1 = (const float*)d_in[7];
    float* out = (float*)d_out;

    char* wp = (char*)d_ws;
    size_t off = 0;
    auto A = [&](size_t bytes) -> void* {
        void* p = wp + off;
        off += (bytes + 255) & ~(size_t)255;
        return p;
    };
    float* feats1  = (float*)A((size_t)B*N1*C0*4);
    int*   fi1     = (int*)  A((size_t)B*G1*4);
    float* lcx1    = (float*)A((size_t)B*G1*3*4);
    float* lcf1    = (float*)A((size_t)B*G1*C0*4);
    int*   ki1     = (int*)  A((size_t)B*G1*KNB*4);
    double* acc    = (double*)A(8*8);
    double* part   = (double*)A((size_t)B*G1*4*8);
    double* bnpart = (double*)A((size_t)NB*Co2*2*8);
    float* stats   = (float*)A((size_t)Co2*2*4);
    float* pooled1 = (float*)A((size_t)B*G1*Co1*4);
    float* feats2  = (float*)A((size_t)B*N2*C1*4);
    float* lcx2    = (float*)A((size_t)B*G2*3*4);
    // aliases (lifetimes disjoint, sizes equal)
    float* lcf2    = lcf1;     // B*G2*C1 == B*G1*C0
    int*   ki2     = ki1;
    float* pooled2 = feats1;   // B*G2*Co2 == B*N1*C0

    // 1. transpose (tiled, both sides coalesced)
    {
        dim3 grid((N1 + 31) / 32, (C0 + 31) / 32, B);
        k_transpose<<<grid, dim3(32, 8), 0, stream>>>(x0, feats1, C0, N1);
    }

    // ---- stage 1 ----
    // 2. FPS (frozen)
    {
        size_t poff = ((size_t)(2*4*8) + (size_t)G1*4 + 15) & ~(size_t)15;
        size_t shm = poff + (size_t)N1*16;
        k_fps_t<16, 4><<<B, 256, shm, stream>>>(xyz, fi1, N1, G1);
    }
    // 3. kNN + gather + fused std partials
    k_knn_t<16><<<B*G1, 256, 0, stream>>>(xyz, feats1, fi1, lcx1, lcf1, ki1, part,
                                          B, N1, G1, C0, 0);
    // 4. partials -> acc[0..3]
    k_reduce<<<1, 1024, 0, stream>>>(part, acc, B*G1);
    // 5. feature + pool -> pooled1 [B,G1,Co1]
    {
        size_t shf = (size_t)(KNB*7 + KNB*3 + KNB + 2*KNB*C0) * 4;
        k_feature<<<B*G1, 256, shf, stream>>>(xyz, feats1, lcx1, lcf1, ki1, B0, acc, pooled1,
                                              B, N1, G1, C0,
                                              (double)B*G1*KNB*C0, (double)B*G1*KNB*3);
    }
    // 6. BN stats + apply (elementwise: pooled1 [B,G,Cout] -> feats2 [B,G,Cout])
    k_bnstat<<<NB, 256, 0, stream>>>(pooled1, bnpart, B*G1, Co1, (B*G1 + NB - 1)/NB);
    k_bnfin<<<1, 512, 0, stream>>>(bnpart, stats, NB, Co1, (double)(B*G1));
    k_bnapply<<<(B*G1*Co1 + 255)/256, 256, 0, stream>>>(pooled1, stats, g0, be0, feats2,
                                                        B*G1*Co1, Co1);

    // ---- stage 2 (xyz = lcx1, feats = feats2) ----
    // FPS on an FPS-ordered prefix set is the identity permutation (prefix-nesting).
    // 7. kNN + identity gather + fused std partials
    k_knn_t<8><<<B*G2, 256, 0, stream>>>(lcx1, feats2, (const int*)nullptr,
                                         lcx2, lcf2, ki2, part, B, N2, G2, C1, 1);
    // 8. partials -> acc[4..7]
    k_reduce<<<1, 1024, 0, stream>>>(part, acc + 4, B*G2);
    // 9. feature + pool -> pooled2 [B,G2,Co2]
    {
        size_t shf = (size_t)(KNB*7 + KNB*3 + KNB + 2*KNB*C1) * 4;
        k_feature<<<B*G2, 256, shf, stream>>>(lcx1, feats2, lcx2, lcf2, ki2, B1, acc + 4, pooled2,
                                              B, N2, G2, C1,
                                              (double)B*G2*KNB*C1, (double)B*G2*KNB*3);
    }
    // 10. BN stats + apply w/ tiled transpose -> out [B,Co2,G2]
    k_bnstat<<<NB, 256, 0, stream>>>(pooled2, bnpart, B*G2, Co2, (B*G2 + NB - 1)/NB);
    k_bnfin<<<1, 512, 0, stream>>>(bnpart, stats, NB, Co2, (double)(B*G2));
    {
        dim3 grid((G2 + 31) / 32, (Co2 + 31) / 32, B);
        k_bnapply_t<<<grid, dim3(32, 8), 0, stream>>>(pooled2, stats, g1, be1, out, G2, Co2);
    }
}

// Round 14
// 1664.426 us; speedup vs baseline: 1.0341x; 1.0341x over previous
//
#include <hip/hip_runtime.h>
#include <math.h>

#define KNB 24

typedef float v2f __attribute__((ext_vector_type(2)));

// ---------------------------------------------------------------- tiled transpose + zero acc
// x [B,C,N] -> feats [B,N,C]; 32x32 LDS tiles, both sides coalesced.
__global__ __launch_bounds__(256) void k_transpose(const float* __restrict__ x,
                                                   float* __restrict__ feats,
                                                   double* __restrict__ acc,
                                                   int C, int N) {
    __shared__ float tile[32][33];
    if (blockIdx.x == 0 && blockIdx.y == 0 && blockIdx.z == 0 &&
        threadIdx.y == 0 && threadIdx.x < 8) acc[threadIdx.x] = 0.0;
    int b = blockIdx.z;
    int n0 = blockIdx.x * 32, c0 = blockIdx.y * 32;
    int tx = threadIdx.x, ty = threadIdx.y;      // block (32,8)
#pragma unroll
    for (int k = 0; k < 4; ++k) {
        int c = c0 + ty + k * 8, n = n0 + tx;
        if (c < C && n < N) tile[ty + k * 8][tx] = x[((size_t)b * C + c) * N + n];
    }
    __syncthreads();
#pragma unroll
    for (int k = 0; k < 4; ++k) {
        int n = n0 + ty + k * 8, c = c0 + tx;
        if (c < C && n < N) feats[((size_t)b * N + n) * C + c] = tile[tx][ty + k * 8];
    }
}

// ---------------------------------------------------------------- DPP reduce helpers
template<int CTRL>
__device__ __forceinline__ float dppmax(float v) {
    int t = __builtin_amdgcn_update_dpp(0, __float_as_int(v), CTRL, 0xf, 0xf, true);
    return fmaxf(v, __int_as_float(t));
}
template<int CTRL>
__device__ __forceinline__ unsigned dppmaxu(unsigned v) {
    unsigned t = (unsigned)__builtin_amdgcn_update_dpp(0, (int)v, CTRL, 0xf, 0xf, true);
    return v > t ? v : t;
}

// ---------------------------------------------------------------- FPS (frozen: floor of 8 variants)
template<int NPT, int NWAVE>   // NPT even
__global__ __launch_bounds__(64 * NWAVE) void k_fps_t(const float* __restrict__ xyz,
                                                      int* __restrict__ fi,
                                                      int N, int M) {
#pragma clang fp contract(off)
    const int NP2 = NPT / 2;
    const int b = blockIdx.x;
    const int tid = threadIdx.x;
    const int lane = tid & 63;
    const int wid = tid >> 6;
    extern __shared__ char smc[];
    unsigned long long* keys = (unsigned long long*)smc;   // [2][NWAVE] parity dbuf
    int* fi_lds = (int*)(smc + 2 * NWAVE * 8);             // [M]
    size_t poff = ((size_t)(2 * NWAVE * 8) + (size_t)M * 4 + 15) & ~(size_t)15;
    float4* pts = (float4*)(smc + poff);                   // [N] packed xyz

    const float* p = xyz + (size_t)b * N * 3;
    for (int i = tid; i < N; i += 64 * NWAVE)
        pts[i] = make_float4(p[i*3], p[i*3+1], p[i*3+2], 0.0f);
    __syncthreads();

    const int base = tid * NPT;
    v2f rx[NP2], ry[NP2], rz[NP2], dist[NP2];
#pragma unroll
    for (int j = 0; j < NP2; ++j) {
        float4 a = pts[base + 2*j];
        float4 c = pts[base + 2*j + 1];
        rx[j] = (v2f){a.x, c.x}; ry[j] = (v2f){a.y, c.y}; rz[j] = (v2f){a.z, c.z};
        dist[j] = (v2f){1e10f, 1e10f};
    }

    int far = 0;
    float4 cpt = pts[0];
    float cx = cpt.x, cy = cpt.y, cz = cpt.z;
    for (int it = 0; it < M; ++it) {
        if (tid == 0) fi_lds[it] = far;               // record carry BEFORE update
        v2f cx2 = (v2f){cx, cx}, cy2 = (v2f){cy, cy}, cz2 = (v2f){cz, cz};
        v2f bv2 = (v2f){-1.0f, -1.0f};
#pragma unroll
        for (int j = 0; j < NP2; ++j) {
            v2f dx = rx[j] - cx2, dy = ry[j] - cy2, dz = rz[j] - cz2;
            v2f d = (dx*dx + dy*dy) + dz*dz;          // ((d0+d1)+d2) per elem, no fma
            v2f dd = __builtin_elementwise_min(dist[j], d);
            dist[j] = dd;
            bv2 = __builtin_elementwise_max(bv2, dd);
        }
        float bv = fmaxf(bv2.x, bv2.y);
        int bi = 0;
#pragma unroll
        for (int j = NP2 - 1; j >= 0; --j) {
            if (dist[j].y == bv) bi = base + 2*j + 1;
            if (dist[j].x == bv) bi = base + 2*j;
        }
        float r = bv;
        r = dppmax<0x111>(r); r = dppmax<0x112>(r);
        r = dppmax<0x114>(r); r = dppmax<0x118>(r);
        r = dppmax<0x142>(r); r = dppmax<0x143>(r);
        float wmax = __int_as_float(__builtin_amdgcn_readlane(__float_as_int(r), 63));
        unsigned long long mask = __ballot(bv == wmax);
        int src = __builtin_ctzll(mask);
        int wbi = __builtin_amdgcn_readlane(bi, src);
        unsigned long long key =
            ((unsigned long long)__float_as_uint(wmax) << 32) | (unsigned)(~wbi);
        if (lane == 0) keys[(it & 1) * NWAVE + wid] = key;
        __syncthreads();
        unsigned long long k0 = keys[(it & 1) * NWAVE + 0];
#pragma unroll
        for (int w = 1; w < NWAVE; ++w) {
            unsigned long long kw = keys[(it & 1) * NWAVE + w];
            if (kw > k0) k0 = kw;
        }
        far = (int)(~(unsigned)k0);
        float4 c = pts[far];                           // single ds_read_b128
        cx = c.x; cy = c.y; cz = c.z;
    }
    __syncthreads();
    for (int i = tid; i < M; i += 64 * NWAVE) fi[b * M + i] = fi_lds[i];
}

// ---------------------------------------------------------------- kNN at WAVE scope
// One wave per bg (4 bgs per block). dists register-resident, contiguous per-lane
// ownership [lane*NPTW,(lane+1)*NPTW). Selection rounds are wave-local: reg scan +
// DPP max on inverted bits + ballot/ctz/readlane — NO barriers, NO LDS exchange.
// Tie semantics identical to the proven R9 logic. Then per-wave gather + std partials.
template<int NPTW>
__global__ __launch_bounds__(256) void k_knn_w(const float* __restrict__ xyz,
                                               const float* __restrict__ feats,
                                               const int* __restrict__ fi,
                                               float* __restrict__ lc_xyz,
                                               float* __restrict__ lc_x,
                                               int* __restrict__ ki,
                                               double* __restrict__ part,
                                               int B, int N, int G, int C, int identity) {
#pragma clang fp contract(off)
    const int lane = threadIdx.x & 63;
    const int wid = threadIdx.x >> 6;
    int bg = blockIdx.x * 4 + wid;
    int b = bg / G, g = bg % G;
    int idx = identity ? g : fi[bg];
    __shared__ float cfeatS[4][144];            // center feats per wave (C <= 144)
    __shared__ int kisS[4][KNB];
    const float* p = xyz + (size_t)b * N * 3;
    float cx = p[idx*3], cy = p[idx*3+1], cz = p[idx*3+2];
    if (lane < 3) lc_xyz[(size_t)bg * 3 + lane] = p[idx*3 + lane];
    for (int c = lane; c < C; c += 64) {
        float v = feats[((size_t)b * N + idx) * C + c];
        lc_x[(size_t)bg * C + c] = v;
        cfeatS[wid][c] = v;
    }
    float cc = (cx*cx + cy*cy) + cz*cz;
    const int base = lane * NPTW;
    float dist[NPTW];
#pragma unroll
    for (int j = 0; j < NPTW; ++j) {
        float x0 = p[(base+j)*3], x1 = p[(base+j)*3+1], x2 = p[(base+j)*3+2];
        float xx = (x0*x0 + x1*x1) + x2*x2;
        float dt = (cx*x0 + cy*x1) + cz*x2;
        dist[j] = (cc - 2.0f*dt) + xx;        // (cc - 2dot) + xx, matches ref assoc
    }
    for (int kk = 0; kk < KNB; ++kk) {
        float bv = 1e30f;
#pragma unroll
        for (int j = 0; j < NPTW; ++j) bv = fminf(bv, dist[j]);
        int lj = 0;
#pragma unroll
        for (int j = NPTW - 1; j >= 0; --j) if (dist[j] == bv) lj = j;  // first-min
        unsigned ub = ~__float_as_uint(bv);
        unsigned r = ub;
        r = dppmaxu<0x111>(r); r = dppmaxu<0x112>(r);
        r = dppmaxu<0x114>(r); r = dppmaxu<0x118>(r);
        r = dppmaxu<0x142>(r); r = dppmaxu<0x143>(r);
        unsigned uwin = (unsigned)__builtin_amdgcn_readlane((int)r, 63);
        unsigned long long mask = __ballot(ub == uwin);
        int src = __builtin_ctzll(mask);
        int gi = __builtin_amdgcn_readlane(base + lj, src);   // wave-uniform
        if (lane == 0) kisS[wid][kk] = gi;
        if (gi >= base && gi < base + NPTW) {     // winner lane invalidates
            int wj = gi - base;
#pragma unroll
            for (int j = 0; j < NPTW; ++j) if (j == wj) dist[j] = 1e30f;
        }
    }
    if (lane < KNB) ki[(size_t)bg * KNB + lane] = kisS[wid][lane];
    // per-wave std partial sums (kisS/cfeatS wave-coherent; no barrier needed)
    double s = 0.0, s2 = 0.0, s3 = 0.0, s4 = 0.0;
    for (int i = lane; i < KNB * C; i += 64) {
        int k = i / C, c = i - k * C;
        float d = feats[((size_t)b * N + kisS[wid][k]) * C + c] - cfeatS[wid][c];
        s += (double)d; s2 += (double)d * (double)d;
    }
    for (int i = lane; i < KNB * 3; i += 64) {
        int k = i / 3, c = i - k * 3;
        float ctr = (c == 0) ? cx : ((c == 1) ? cy : cz);
        float d = p[kisS[wid][k] * 3 + c] - ctr;
        s3 += (double)d; s4 += (double)d * (double)d;
    }
#pragma unroll
    for (int off = 32; off > 0; off >>= 1) {
        s += __shfl_down(s, off); s2 += __shfl_down(s2, off);
        s3 += __shfl_down(s3, off); s4 += __shfl_down(s4, off);
    }
    if (lane == 0) {
        double* q = part + (size_t)bg * 4;
        q[0] = s; q[1] = s2; q[2] = s3; q[3] = s4;
    }
}

// ---------------------------------------------------------------- per-block partials -> acc[0..3]
__global__ __launch_bounds__(1024) void k_reduce(const double* __restrict__ part,
                                                 double* __restrict__ acc, int n) {
    double s0 = 0.0, s1 = 0.0, s2 = 0.0, s3 = 0.0;
    for (int i = threadIdx.x; i < n; i += 1024) {
        const double* q = part + (size_t)i * 4;
        s0 += q[0]; s1 += q[1]; s2 += q[2]; s3 += q[3];
    }
    for (int off = 32; off > 0; off >>= 1) {
        s0 += __shfl_down(s0, off); s1 += __shfl_down(s1, off);
        s2 += __shfl_down(s2, off); s3 += __shfl_down(s3, off);
    }
    __shared__ double sw[16][4];
    int wid = threadIdx.x >> 6;
    if ((threadIdx.x & 63) == 0) {
        sw[wid][0] = s0; sw[wid][1] = s1; sw[wid][2] = s2; sw[wid][3] = s3;
    }
    __syncthreads();
    if (threadIdx.x == 0) {
        double t0 = 0.0, t1 = 0.0, t2 = 0.0, t3 = 0.0;
        for (int w = 0; w < 16; ++w) {
            t0 += sw[w][0]; t1 += sw[w][1]; t2 += sw[w][2]; t3 += sw[w][3];
        }
        acc[0] = t0; acc[1] = t1; acc[2] = t2; acc[3] = t3;
    }
}

// ---------------------------------------------------------------- LGA feature + pool (R12-exact)
__global__ __launch_bounds__(256) void k_feature(
    const float* __restrict__ xyz, const float* __restrict__ feats,
    const float* __restrict__ lc_xyz, const float* __restrict__ lc_x,
    const int* __restrict__ ki, const float* __restrict__ Bmat,
    const double* __restrict__ accp, float* __restrict__ pooled,
    int B, int N, int G, int C, double nx, double nz)
{
    int bg = blockIdx.x; int b = bg / G; int g = bg % G;
    int tid = threadIdx.x;
    int C2 = C >> 1;
    int Cout = 2 * C;
    int F = C / 3;                         // tr_embed F = (2C)/(2*3)
    extern __shared__ float sm[];
    float* t7    = sm;                     // [24][7]
    float* sxyzn = t7 + KNB * 7;           // [24][3]
    int*   kidx  = (int*)(sxyzn + KNB * 3);// [24]
    float* semb  = (float*)(kidx + KNB);   // [24][C]
    float* sfeat = semb + KNB * C;         // [24][C]

    double a0 = accp[0], a1 = accp[1], a2 = accp[2], a3 = accp[3];
    double vx = (a1 - a0 * a0 / nx) / (nx - 1.0);
    float invx = 1.0f / (sqrtf((float)vx) + 1e-5f);
    double vz = (a3 - a2 * a2 / nz) / (nz - 1.0);
    float invz = 1.0f / (sqrtf((float)vz) + 1e-5f);

    float l0 = lc_xyz[(size_t)bg*3], l1 = lc_xyz[(size_t)bg*3+1], l2 = lc_xyz[(size_t)bg*3+2];

    if (tid < KNB) {
        int idx = ki[(size_t)bg * KNB + tid];
        kidx[tid] = idx;
        const float* q = xyz + ((size_t)b * N + idx) * 3;
        float a0f = (q[0]-l0)*invz, a1f = (q[1]-l1)*invz, a2f = (q[2]-l2)*invz;
        float c0 = a1f*l2 - a2f*l1;        // cross(normed knn_xyz, raw lc_xyz)
        float c1 = a2f*l0 - a0f*l2;
        float c2 = a0f*l1 - a1f*l0;
        float dt = (a0f*l0 + a1f*l1) + a2f*l2;
        float* tp = t7 + tid * 7;
        tp[0]=a0f; tp[1]=a1f; tp[2]=a2f; tp[3]=c0; tp[4]=c1; tp[5]=c2; tp[6]=dt;
        sxyzn[tid*3]=a0f; sxyzn[tid*3+1]=a1f; sxyzn[tid*3+2]=a2f;
    }
    __syncthreads();
    // stage knn feature rows (coalesced row loads)
    for (int i = tid; i < KNB * C; i += blockDim.x) {
        int k = i / C, c = i - k * C;
        sfeat[i] = feats[((size_t)b * N + kidx[k]) * C + c];
    }
    const float TWO_PI = 6.2831854820251465f;
    for (int i = tid; i < KNB * C2; i += blockDim.x) {
        int k = i / C2, m2 = i % C2;
        const float* tp = t7 + k * 7;
        float s = 0.0f;
        for (int j = 0; j < 7; ++j) s += tp[j] * Bmat[j * C2 + m2];
        float pr = TWO_PI * s;
        float sn, cs;
        __sincosf(pr, &sn, &cs);
        float sn2 = sn*sn, cs2 = cs*cs;
        semb[k*C + m2]      = sn2*sn2*sn;
        semb[k*C + C2 + m2] = cs2*cs2*cs;
    }
    __syncthreads();
    for (int m = tid; m < Cout; m += blockDim.x) {
        int c3 = m / (2 * F);
        int r  = m % (2 * F);
        int f  = r >> 1;
        int trig = r & 1;
        float de = __powf(100.0f, (float)f / (float)F);
        float rde = 1000.0f / de;          // hoisted: k-loop uses mul, not div
        float lv = (c3 == 0) ? l0 : ((c3 == 1) ? l1 : l2);
        float a2v = lv * rde;
        float pe2 = trig ? __cosf(a2v) : __sinf(a2v);
        float lfm = (m < C) ? lc_x[(size_t)bg * C + m] : 0.0f;
        float acc = 0.0f;
        for (int k = 0; k < KNB; ++k) {
            float v;
            if (m < C) {
                v = (sfeat[k * C + m] - lfm) * invx;
            } else {
                v = semb[k * C + (m - C)];
            }
            float a1v = sxyzn[k*3 + c3] * rde;
            float pe1 = trig ? __cosf(a1v) : __sinf(a1v);
            float pe = pe1 + pe2;
            acc += (v + pe) * pe;
        }
        float mean = acc / 24.0f;
        pooled[((size_t)b * Cout + m) * G + g] = 2.0f * mean;   // k_anp + mean = 2*mean
    }
}

// ---------------------------------------------------------------- fused BatchNorm(train) + exact GELU (R12-exact)
__global__ __launch_bounds__(256) void k_bn(const float* __restrict__ pooled,
                                            const float* __restrict__ gamma,
                                            const float* __restrict__ beta,
                                            float* __restrict__ out,
                                            int B, int Cout, int G, int transposed) {
    int m = blockIdx.x;
    double s = 0.0, s2 = 0.0;
    for (int i = threadIdx.x; i < B * G; i += 256) {
        int b = i / G, g = i % G;
        float v = pooled[((size_t)b * Cout + m) * G + g];
        s += (double)v; s2 += (double)v * (double)v;
    }
    for (int off = 32; off > 0; off >>= 1) { s += __shfl_down(s, off); s2 += __shfl_down(s2, off); }
    __shared__ double sw[4], sw2[4];
    __shared__ float smv[2];
    int wid = threadIdx.x >> 6;
    if ((threadIdx.x & 63) == 0) { sw[wid] = s; sw2[wid] = s2; }
    __syncthreads();
    if (threadIdx.x == 0) {
        double ts = sw[0] + sw[1] + sw[2] + sw[3];
        double ts2 = sw2[0] + sw2[1] + sw2[2] + sw2[3];
        double n = (double)(B * G);
        double mean = ts / n;
        double var = ts2 / n - mean * mean;
        smv[0] = (float)mean; smv[1] = (float)var;
    }
    __syncthreads();
    float mean = smv[0], var = smv[1];
    float ga = gamma[m], be = beta[m];
    for (int i = threadIdx.x; i < B * G; i += 256) {
        int b = i / G, g = i % G;
        float v = pooled[((size_t)b * Cout + m) * G + g];
        float y = (v - mean) / sqrtf(var + 1e-5f) * ga + be;
        float ge = 0.5f * y * (1.0f + erff(y / 1.4142135381698608f));
        if (transposed) out[((size_t)b * G + g) * Cout + m] = ge;
        else            out[((size_t)b * Cout + m) * G + g] = ge;
    }
}

// ---------------------------------------------------------------- launch
extern "C" void kernel_launch(void* const* d_in, const int* in_sizes, int n_in,
                              void* d_out, int out_size, void* d_ws, size_t ws_size,
                              hipStream_t stream) {
    const int B = 4, N1 = 4096, C0 = 72, G1 = 2048, Co1 = 144;
    const int N2 = 2048, C1 = 144, G2 = 1024, Co2 = 288;

    const float* xyz = (const float*)d_in[0];
    const float* x0  = (const float*)d_in[1];
    const float* B0  = (const float*)d_in[2];
    const float* B1  = (const float*)d_in[3];
    const float* g0  = (const float*)d_in[4];
    const float* be0 = (const float*)d_in[5];
    const float* g1  = (const float*)d_in[6];
    const float* be1 = (const float*)d_in[7];
    float* out = (float*)d_out;

    char* wp = (char*)d_ws;
    size_t off = 0;
    auto A = [&](size_t bytes) -> void* {
        void* p = wp + off;
        off += (bytes + 255) & ~(size_t)255;
        return p;
    };
    float* feats1  = (float*)A((size_t)B*N1*C0*4);
    int*   fi1     = (int*)  A((size_t)B*G1*4);
    float* lcx1    = (float*)A((size_t)B*G1*3*4);
    float* lcf1    = (float*)A((size_t)B*G1*C0*4);
    int*   ki1     = (int*)  A((size_t)B*G1*KNB*4);
    double* acc    = (double*)A(8*8);
    double* part   = (double*)A((size_t)B*G1*4*8);
    float* pooled1 = (float*)A((size_t)B*Co1*G1*4);
    float* feats2  = (float*)A((size_t)B*N2*C1*4);
    float* lcx2    = (float*)A((size_t)B*G2*3*4);
    // aliases (lifetimes disjoint, sizes equal)
    float* lcf2    = lcf1;     // B*G2*C1 == B*G1*C0
    int*   ki2     = ki1;
    float* pooled2 = feats1;   // B*Co2*G2 == B*N1*C0

    // 1. tiled transpose + zero acc
    {
        dim3 grid((N1 + 31) / 32, (C0 + 31) / 32, B);
        k_transpose<<<grid, dim3(32, 8), 0, stream>>>(x0, feats1, acc, C0, N1);
    }

    // ---- stage 1 ----
    // 2. FPS (frozen)
    {
        size_t poff = ((size_t)(2*4*8) + (size_t)G1*4 + 15) & ~(size_t)15;
        size_t shm = poff + (size_t)N1*16;
        k_fps_t<16, 4><<<B, 256, shm, stream>>>(xyz, fi1, N1, G1);
    }
    // 3. kNN (wave-scope) + gather + std partials
    k_knn_w<64><<<B*G1/4, 256, 0, stream>>>(xyz, feats1, fi1, lcx1, lcf1, ki1, part,
                                            B, N1, G1, C0, 0);
    // 4. partials -> acc[0..3]
    k_reduce<<<1, 1024, 0, stream>>>(part, acc, B*G1);
    // 5. feature + pool (R12: pooled [B,Cout,G])
    {
        size_t shf = (size_t)(KNB*7 + KNB*3 + KNB + 2*KNB*C0) * 4;
        k_feature<<<B*G1, 256, shf, stream>>>(xyz, feats1, lcx1, lcf1, ki1, B0, acc, pooled1,
                                              B, N1, G1, C0,
                                              (double)B*G1*KNB*C0, (double)B*G1*KNB*3);
    }
    // 6. BN + GELU (transposed -> feats layout for stage 2)
    k_bn<<<Co1, 256, 0, stream>>>(pooled1, g0, be0, feats2, B, Co1, G1, 1);

    // ---- stage 2 (xyz = lcx1, feats = feats2) ----
    // FPS on an FPS-ordered prefix set is the identity permutation (prefix-nesting).
    // 7. kNN (wave-scope) + identity gather + std partials
    k_knn_w<32><<<B*G2/4, 256, 0, stream>>>(lcx1, feats2, (const int*)nullptr,
                                            lcx2, lcf2, ki2, part, B, N2, G2, C1, 1);
    // 8. partials -> acc[4..7]
    k_reduce<<<1, 1024, 0, stream>>>(part, acc + 4, B*G2);
    // 9. feature + pool
    {
        size_t shf = (size_t)(KNB*7 + KNB*3 + KNB + 2*KNB*C1) * 4;
        k_feature<<<B*G2, 256, shf, stream>>>(lcx1, feats2, lcx2, lcf2, ki2, B1, acc + 4, pooled2,
                                              B, N2, G2, C1,
                                              (double)B*G2*KNB*C1, (double)B*G2*KNB*3);
    }
    // 10. BN + GELU -> final output
    k_bn<<<Co2, 256, 0, stream>>>(pooled2, g1, be1, out, B, Co2, G2, 0);
}

// Round 15
// 1645.085 us; speedup vs baseline: 1.0463x; 1.0118x over previous
//
#include <hip/hip_runtime.h>
#include <math.h>

#define KNB 24

typedef float v2f __attribute__((ext_vector_type(2)));

// ---------------------------------------------------------------- DPP reduce helpers
template<int CTRL>
__device__ __forceinline__ float dppmax(float v) {
    int t = __builtin_amdgcn_update_dpp(0, __float_as_int(v), CTRL, 0xf, 0xf, true);
    return fmaxf(v, __int_as_float(t));
}
template<int CTRL>
__device__ __forceinline__ unsigned dppmaxu(unsigned v) {
    unsigned t = (unsigned)__builtin_amdgcn_update_dpp(0, (int)v, CTRL, 0xf, 0xf, true);
    return v > t ? v : t;
}

// ---------------------------------------------------------------- FPS + fused transpose
// Blocks [0,B): FPS (frozen R5/R12 config — floor of 8 variants).
// Blocks [B, B+B*cT*nT): 32x32 tiled transpose x[B,C,N]->feats[B,N,C] on the
// 252 CUs that FPS leaves idle (no data dependency -> dispatch-order safe).
template<int NPT, int NWAVE>   // NPT even
__global__ __launch_bounds__(64 * NWAVE) void k_fps_tr(const float* __restrict__ xyz,
                                                       int* __restrict__ fi,
                                                       int N, int M,
                                                       const float* __restrict__ x0,
                                                       float* __restrict__ feats,
                                                       int C, int NT, int nT, int cT) {
#pragma clang fp contract(off)
    const int NP2 = NPT / 2;
    const int tid = threadIdx.x;
    extern __shared__ char smc[];

    if ((int)blockIdx.x >= gridDim.x - 0 && false) return;  // (keep compiler calm)

    if ((int)blockIdx.x >= (int)(gridDim.x) ) return;

    if ((int)blockIdx.x >= (int)0 && (int)blockIdx.x >= (int)(/*B*/ 0) && false) return;

    // ---- transpose blocks ----
    if ((int)blockIdx.x >= (int)( (int)gridDim.x - nT * cT * 4 ) && (int)blockIdx.x >= 4) {
        int bid = blockIdx.x - 4;                 // B = 4 fixed for this problem
        int tilesPerB = nT * cT;
        int b = bid / tilesPerB;
        int t2 = bid - b * tilesPerB;
        int cTile = t2 / nT;
        int nTile = t2 - cTile * nT;
        int tx = tid & 31, ty = tid >> 5;         // 32 x 8
        float* tile = (float*)smc;                // 32 x 33
#pragma unroll
        for (int k = 0; k < 4; ++k) {
            int c = cTile * 32 + ty + k * 8, n = nTile * 32 + tx;
            if (c < C && n < NT) tile[(ty + k * 8) * 33 + tx] = x0[((size_t)b * C + c) * NT + n];
        }
        __syncthreads();
#pragma unroll
        for (int k = 0; k < 4; ++k) {
            int n = nTile * 32 + ty + k * 8, c = cTile * 32 + tx;
            if (c < C && n < NT) feats[((size_t)b * NT + n) * C + c] = tile[tx * 33 + ty + k * 8];
        }
        return;
    }

    // ---- FPS blocks ----
    const int b = blockIdx.x;
    const int lane = tid & 63;
    const int wid = tid >> 6;
    unsigned long long* keys = (unsigned long long*)smc;   // [2][NWAVE] parity dbuf
    int* fi_lds = (int*)(smc + 2 * NWAVE * 8);             // [M]
    size_t poff = ((size_t)(2 * NWAVE * 8) + (size_t)M * 4 + 15) & ~(size_t)15;
    float4* pts = (float4*)(smc + poff);                   // [N] packed xyz

    const float* p = xyz + (size_t)b * N * 3;
    for (int i = tid; i < N; i += 64 * NWAVE)
        pts[i] = make_float4(p[i*3], p[i*3+1], p[i*3+2], 0.0f);
    __syncthreads();

    const int base = tid * NPT;
    v2f rx[NP2], ry[NP2], rz[NP2], dist[NP2];
#pragma unroll
    for (int j = 0; j < NP2; ++j) {
        float4 a = pts[base + 2*j];
        float4 c = pts[base + 2*j + 1];
        rx[j] = (v2f){a.x, c.x}; ry[j] = (v2f){a.y, c.y}; rz[j] = (v2f){a.z, c.z};
        dist[j] = (v2f){1e10f, 1e10f};
    }

    int far = 0;
    float4 cpt = pts[0];
    float cx = cpt.x, cy = cpt.y, cz = cpt.z;
    for (int it = 0; it < M; ++it) {
        if (tid == 0) fi_lds[it] = far;               // record carry BEFORE update
        v2f cx2 = (v2f){cx, cx}, cy2 = (v2f){cy, cy}, cz2 = (v2f){cz, cz};
        v2f bv2 = (v2f){-1.0f, -1.0f};
#pragma unroll
        for (int j = 0; j < NP2; ++j) {
            v2f dx = rx[j] - cx2, dy = ry[j] - cy2, dz = rz[j] - cz2;
            v2f d = (dx*dx + dy*dy) + dz*dz;          // ((d0+d1)+d2) per elem, no fma
            v2f dd = __builtin_elementwise_min(dist[j], d);
            dist[j] = dd;
            bv2 = __builtin_elementwise_max(bv2, dd);
        }
        float bv = fmaxf(bv2.x, bv2.y);
        int bi = 0;
#pragma unroll
        for (int j = NP2 - 1; j >= 0; --j) {
            if (dist[j].y == bv) bi = base + 2*j + 1;
            if (dist[j].x == bv) bi = base + 2*j;
        }
        float r = bv;
        r = dppmax<0x111>(r); r = dppmax<0x112>(r);
        r = dppmax<0x114>(r); r = dppmax<0x118>(r);
        r = dppmax<0x142>(r); r = dppmax<0x143>(r);
        float wmax = __int_as_float(__builtin_amdgcn_readlane(__float_as_int(r), 63));
        unsigned long long mask = __ballot(bv == wmax);
        int src = __builtin_ctzll(mask);
        int wbi = __builtin_amdgcn_readlane(bi, src);
        unsigned long long key =
            ((unsigned long long)__float_as_uint(wmax) << 32) | (unsigned)(~wbi);
        if (lane == 0) keys[(it & 1) * NWAVE + wid] = key;
        __syncthreads();
        unsigned long long k0 = keys[(it & 1) * NWAVE + 0];
#pragma unroll
        for (int w = 1; w < NWAVE; ++w) {
            unsigned long long kw = keys[(it & 1) * NWAVE + w];
            if (kw > k0) k0 = kw;
        }
        far = (int)(~(unsigned)k0);
        float4 c = pts[far];                           // single ds_read_b128
        cx = c.x; cy = c.y; cz = c.z;
    }
    __syncthreads();
    for (int i = tid; i < M; i += 64 * NWAVE) fi[b * M + i] = fi_lds[i];
}

// ---------------------------------------------------------------- kNN + gather + fused std partials (R12-exact)
template<int NPT>
__global__ __launch_bounds__(256) void k_knn_t(const float* __restrict__ xyz,
                                               const float* __restrict__ feats,
                                               const int* __restrict__ fi,
                                               float* __restrict__ lc_xyz,
                                               float* __restrict__ lc_x,
                                               int* __restrict__ ki,
                                               double* __restrict__ part,
                                               int B, int N, int G, int C, int identity) {
#pragma clang fp contract(off)
    int bg = blockIdx.x; int b = bg / G; int g = bg % G;
    int idx = identity ? g : fi[bg];
    const int tid = threadIdx.x;
    const int lane = tid & 63;
    const int wid = tid >> 6;
    __shared__ unsigned long long keys[2][4];   // parity dbuf
    __shared__ int kis[KNB];
    __shared__ float cfeat[144];                // center feats cache (C <= 144)
    const float* p = xyz + (size_t)b * N * 3;
    float cx = p[idx*3], cy = p[idx*3+1], cz = p[idx*3+2];
    if (tid < 3) lc_xyz[(size_t)bg * 3 + tid] = p[idx*3 + tid];
    for (int c = tid; c < C; c += 256) {
        float v = feats[((size_t)b * N + idx) * C + c];
        lc_x[(size_t)bg * C + c] = v;
        cfeat[c] = v;
    }
    float cc = (cx*cx + cy*cy) + cz*cz;
    const int base = tid * NPT;
    float dist[NPT];
#pragma unroll
    for (int j = 0; j < NPT; ++j) {
        float x0 = p[(base+j)*3], x1 = p[(base+j)*3+1], x2 = p[(base+j)*3+2];
        float xx = (x0*x0 + x1*x1) + x2*x2;
        float dt = (cx*x0 + cy*x1) + cz*x2;
        dist[j] = (cc - 2.0f*dt) + xx;        // (cc - 2dot) + xx, matches ref assoc
    }
    for (int kk = 0; kk < KNB; ++kk) {
        float bv = 1e30f;
#pragma unroll
        for (int j = 0; j < NPT; ++j) bv = fminf(bv, dist[j]);
        int lj = 0;
#pragma unroll
        for (int j = NPT - 1; j >= 0; --j) if (dist[j] == bv) lj = j;  // first-min
        unsigned ub = ~__float_as_uint(bv);
        unsigned r = ub;
        r = dppmaxu<0x111>(r); r = dppmaxu<0x112>(r);
        r = dppmaxu<0x114>(r); r = dppmaxu<0x118>(r);
        r = dppmaxu<0x142>(r); r = dppmaxu<0x143>(r);
        unsigned uwin = (unsigned)__builtin_amdgcn_readlane((int)r, 63);
        unsigned long long mask = __ballot(ub == uwin);
        int src = __builtin_ctzll(mask);
        int gi = __builtin_amdgcn_readlane(base + lj, src);
        unsigned long long key = ((unsigned long long)uwin << 32) | (unsigned)(~gi);
        if (lane == 0) keys[kk & 1][wid] = key;
        __syncthreads();
        unsigned long long k0 = keys[kk & 1][0];
#pragma unroll
        for (int w = 1; w < 4; ++w) {
            unsigned long long kw = keys[kk & 1][w];
            if (kw > k0) k0 = kw;
        }
        int win = (int)(~(unsigned)k0);
        if (tid == 0) kis[kk] = win;
        if (win >= base && win < base + NPT) {
            int wj = win - base;
#pragma unroll
            for (int j = 0; j < NPT; ++j) if (j == wj) dist[j] = 1e30f;
        }
    }
    __syncthreads();
    if (tid < KNB) ki[(size_t)bg * KNB + tid] = kis[tid];
    // fused std partial sums
    double s = 0.0, s2 = 0.0, s3 = 0.0, s4 = 0.0;
    for (int i = tid; i < KNB * C; i += 256) {
        int k = i / C, c = i - k * C;
        float d = feats[((size_t)b * N + kis[k]) * C + c] - cfeat[c];
        s += (double)d; s2 += (double)d * (double)d;
    }
    if (tid < KNB * 3) {
        int k = tid / 3, c = tid - k * 3;
        float ctr = (c == 0) ? cx : ((c == 1) ? cy : cz);
        float d = p[kis[k] * 3 + c] - ctr;
        s3 += (double)d; s4 += (double)d * (double)d;
    }
    for (int off = 32; off > 0; off >>= 1) {
        s += __shfl_down(s, off); s2 += __shfl_down(s2, off);
        s3 += __shfl_down(s3, off); s4 += __shfl_down(s4, off);
    }
    __shared__ double sw[4][4];
    if ((tid & 63) == 0) {
        sw[wid][0] = s; sw[wid][1] = s2; sw[wid][2] = s3; sw[wid][3] = s4;
    }
    __syncthreads();
    if (tid == 0) {
        double t0 = 0.0, t1 = 0.0, t2 = 0.0, t3 = 0.0;
        for (int w = 0; w < 4; ++w) {
            t0 += sw[w][0]; t1 += sw[w][1]; t2 += sw[w][2]; t3 += sw[w][3];
        }
        double* q = part + (size_t)bg * 4;
        q[0] = t0; q[1] = t1; q[2] = t2; q[3] = t3;
    }
}

// ---------------------------------------------------------------- per-block partials -> acc[0..3]
__global__ __launch_bounds__(1024) void k_reduce(const double* __restrict__ part,
                                                 double* __restrict__ acc, int n) {
    double s0 = 0.0, s1 = 0.0, s2 = 0.0, s3 = 0.0;
    for (int i = threadIdx.x; i < n; i += 1024) {
        const double* q = part + (size_t)i * 4;
        s0 += q[0]; s1 += q[1]; s2 += q[2]; s3 += q[3];
    }
    for (int off = 32; off > 0; off >>= 1) {
        s0 += __shfl_down(s0, off); s1 += __shfl_down(s1, off);
        s2 += __shfl_down(s2, off); s3 += __shfl_down(s3, off);
    }
    __shared__ double sw[16][4];
    int wid = threadIdx.x >> 6;
    if ((threadIdx.x & 63) == 0) {
        sw[wid][0] = s0; sw[wid][1] = s1; sw[wid][2] = s2; sw[wid][3] = s3;
    }
    __syncthreads();
    if (threadIdx.x == 0) {
        double t0 = 0.0, t1 = 0.0, t2 = 0.0, t3 = 0.0;
        for (int w = 0; w < 16; ++w) {
            t0 += sw[w][0]; t1 += sw[w][1]; t2 += sw[w][2]; t3 += sw[w][3];
        }
        acc[0] = t0; acc[1] = t1; acc[2] = t2; acc[3] = t3;
    }
}

// ---------------------------------------------------------------- LGA feature + pool (R12-exact)
__global__ __launch_bounds__(256) void k_feature(
    const float* __restrict__ xyz, const float* __restrict__ feats,
    const float* __restrict__ lc_xyz, const float* __restrict__ lc_x,
    const int* __restrict__ ki, const float* __restrict__ Bmat,
    const double* __restrict__ accp, float* __restrict__ pooled,
    int B, int N, int G, int C, double nx, double nz)
{
    int bg = blockIdx.x; int b = bg / G; int g = bg % G;
    int tid = threadIdx.x;
    int C2 = C >> 1;
    int Cout = 2 * C;
    int F = C / 3;                         // tr_embed F = (2C)/(2*3)
    extern __shared__ float sm[];
    float* t7    = sm;                     // [24][7]
    float* sxyzn = t7 + KNB * 7;           // [24][3]
    int*   kidx  = (int*)(sxyzn + KNB * 3);// [24]
    float* semb  = (float*)(kidx + KNB);   // [24][C]
    float* sfeat = semb + KNB * C;         // [24][C]

    double a0 = accp[0], a1 = accp[1], a2 = accp[2], a3 = accp[3];
    double vx = (a1 - a0 * a0 / nx) / (nx - 1.0);
    float invx = 1.0f / (sqrtf((float)vx) + 1e-5f);
    double vz = (a3 - a2 * a2 / nz) / (nz - 1.0);
    float invz = 1.0f / (sqrtf((float)vz) + 1e-5f);

    float l0 = lc_xyz[(size_t)bg*3], l1 = lc_xyz[(size_t)bg*3+1], l2 = lc_xyz[(size_t)bg*3+2];

    if (tid < KNB) {
        int idx = ki[(size_t)bg * KNB + tid];
        kidx[tid] = idx;
        const float* q = xyz + ((size_t)b * N + idx) * 3;
        float a0f = (q[0]-l0)*invz, a1f = (q[1]-l1)*invz, a2f = (q[2]-l2)*invz;
        float c0 = a1f*l2 - a2f*l1;        // cross(normed knn_xyz, raw lc_xyz)
        float c1 = a2f*l0 - a0f*l2;
        float c2 = a0f*l1 - a1f*l0;
        float dt = (a0f*l0 + a1f*l1) + a2f*l2;
        float* tp = t7 + tid * 7;
        tp[0]=a0f; tp[1]=a1f; tp[2]=a2f; tp[3]=c0; tp[4]=c1; tp[5]=c2; tp[6]=dt;
        sxyzn[tid*3]=a0f; sxyzn[tid*3+1]=a1f; sxyzn[tid*3+2]=a2f;
    }
    __syncthreads();
    // stage knn feature rows (coalesced row loads)
    for (int i = tid; i < KNB * C; i += blockDim.x) {
        int k = i / C, c = i - k * C;
        sfeat[i] = feats[((size_t)b * N + kidx[k]) * C + c];
    }
    const float TWO_PI = 6.2831854820251465f;
    for (int i = tid; i < KNB * C2; i += blockDim.x) {
        int k = i / C2, m2 = i % C2;
        const float* tp = t7 + k * 7;
        float s = 0.0f;
        for (int j = 0; j < 7; ++j) s += tp[j] * Bmat[j * C2 + m2];
        float pr = TWO_PI * s;
        float sn, cs;
        __sincosf(pr, &sn, &cs);
        float sn2 = sn*sn, cs2 = cs*cs;
        semb[k*C + m2]      = sn2*sn2*sn;
        semb[k*C + C2 + m2] = cs2*cs2*cs;
    }
    __syncthreads();
    for (int m = tid; m < Cout; m += blockDim.x) {
        int c3 = m / (2 * F);
        int r  = m % (2 * F);
        int f  = r >> 1;
        int trig = r & 1;
        float de = __powf(100.0f, (float)f / (float)F);
        float rde = 1000.0f / de;          // hoisted: k-loop uses mul, not div
        float lv = (c3 == 0) ? l0 : ((c3 == 1) ? l1 : l2);
        float a2v = lv * rde;
        float pe2 = trig ? __cosf(a2v) : __sinf(a2v);
        float lfm = (m < C) ? lc_x[(size_t)bg * C + m] : 0.0f;
        float acc = 0.0f;
        for (int k = 0; k < KNB; ++k) {
            float v;
            if (m < C) {
                v = (sfeat[k * C + m] - lfm) * invx;
            } else {
                v = semb[k * C + (m - C)];
            }
            float a1v = sxyzn[k*3 + c3] * rde;
            float pe1 = trig ? __cosf(a1v) : __sinf(a1v);
            float pe = pe1 + pe2;
            acc += (v + pe) * pe;
        }
        float mean = acc / 24.0f;
        pooled[((size_t)b * Cout + m) * G + g] = 2.0f * mean;   // k_anp + mean = 2*mean
    }
}

// ---------------------------------------------------------------- fused BatchNorm(train) + exact GELU (R12-exact)
__global__ __launch_bounds__(256) void k_bn(const float* __restrict__ pooled,
                                            const float* __restrict__ gamma,
                                            const float* __restrict__ beta,
                                            float* __restrict__ out,
                                            int B, int Cout, int G, int transposed) {
    int m = blockIdx.x;
    double s = 0.0, s2 = 0.0;
    for (int i = threadIdx.x; i < B * G; i += 256) {
        int b = i / G, g = i % G;
        float v = pooled[((size_t)b * Cout + m) * G + g];
        s += (double)v; s2 += (double)v * (double)v;
    }
    for (int off = 32; off > 0; off >>= 1) { s += __shfl_down(s, off); s2 += __shfl_down(s2, off); }
    __shared__ double sw[4], sw2[4];
    __shared__ float smv[2];
    int wid = threadIdx.x >> 6;
    if ((threadIdx.x & 63) == 0) { sw[wid] = s; sw2[wid] = s2; }
    __syncthreads();
    if (threadIdx.x == 0) {
        double ts = sw[0] + sw[1] + sw[2] + sw[3];
        double ts2 = sw2[0] + sw2[1] + sw2[2] + sw2[3];
        double n = (double)(B * G);
        double mean = ts / n;
        double var = ts2 / n - mean * mean;
        smv[0] = (float)mean; smv[1] = (float)var;
    }
    __syncthreads();
    float mean = smv[0], var = smv[1];
    float ga = gamma[m], be = beta[m];
    for (int i = threadIdx.x; i < B * G; i += 256) {
        int b = i / G, g = i % G;
        float v = pooled[((size_t)b * Cout + m) * G + g];
        float y = (v - mean) / sqrtf(var + 1e-5f) * ga + be;
        float ge = 0.5f * y * (1.0f + erff(y / 1.4142135381698608f));
        if (transposed) out[((size_t)b * G + g) * Cout + m] = ge;
        else            out[((size_t)b * Cout + m) * G + g] = ge;
    }
}

// ---------------------------------------------------------------- launch
extern "C" void kernel_launch(void* const* d_in, const int* in_sizes, int n_in,
                              void* d_out, int out_size, void* d_ws, size_t ws_size,
                              hipStream_t stream) {
    const int B = 4, N1 = 4096, C0 = 72, G1 = 2048, Co1 = 144;
    const int N2 = 2048, C1 = 144, G2 = 1024, Co2 = 288;

    const float* xyz = (const float*)d_in[0];
    const float* x0  = (const float*)d_in[1];
    const float* B0  = (const float*)d_in[2];
    const float* B1  = (const float*)d_in[3];
    const float* g0  = (const float*)d_in[4];
    const float* be0 = (const float*)d_in[5];
    const float* g1  = (const float*)d_in[6];
    const float* be1 = (const float*)d_in[7];
    float* out = (float*)d_out;

    char* wp = (char*)d_ws;
    size_t off = 0;
    auto A = [&](size_t bytes) -> void* {
        void* p = wp + off;
        off += (bytes + 255) & ~(size_t)255;
        return p;
    };
    float* feats1  = (float*)A((size_t)B*N1*C0*4);
    int*   fi1     = (int*)  A((size_t)B*G1*4);
    float* lcx1    = (float*)A((size_t)B*G1*3*4);
    float* lcf1    = (float*)A((size_t)B*G1*C0*4);
    int*   ki1     = (int*)  A((size_t)B*G1*KNB*4);
    double* acc    = (double*)A(8*8);
    double* part   = (double*)A((size_t)B*G1*4*8);
    float* pooled1 = (float*)A((size_t)B*Co1*G1*4);
    float* feats2  = (float*)A((size_t)B*N2*C1*4);
    float* lcx2    = (float*)A((size_t)B*G2*3*4);
    // aliases (lifetimes disjoint, sizes equal)
    float* lcf2    = lcf1;     // B*G2*C1 == B*G1*C0
    int*   ki2     = ki1;
    float* pooled2 = feats1;   // B*Co2*G2 == B*N1*C0

    // ---- stage 1 ----
    // 1+2. FPS (blocks 0..B-1) + transpose x->feats1 (blocks B..) fused in one launch:
    //      the transpose runs on CUs that the 4-block FPS leaves idle.
    {
        const int nT = N1 / 32, cT = (C0 + 31) / 32;   // 128, 3
        size_t poff = ((size_t)(2*4*8) + (size_t)G1*4 + 15) & ~(size_t)15;
        size_t shm = poff + (size_t)N1*16;
        k_fps_tr<16, 4><<<B + B*nT*cT, 256, shm, stream>>>(xyz, fi1, N1, G1,
                                                           x0, feats1, C0, N1, nT, cT);
    }
    // 3. kNN + gather + fused std partials
    k_knn_t<16><<<B*G1, 256, 0, stream>>>(xyz, feats1, fi1, lcx1, lcf1, ki1, part,
                                          B, N1, G1, C0, 0);
    // 4. partials -> acc[0..3]
    k_reduce<<<1, 1024, 0, stream>>>(part, acc, B*G1);
    // 5. feature + pool (pooled [B,Cout,G])
    {
        size_t shf = (size_t)(KNB*7 + KNB*3 + KNB + 2*KNB*C0) * 4;
        k_feature<<<B*G1, 256, shf, stream>>>(xyz, feats1, lcx1, lcf1, ki1, B0, acc, pooled1,
                                              B, N1, G1, C0,
                                              (double)B*G1*KNB*C0, (double)B*G1*KNB*3);
    }
    // 6. BN + GELU (transposed -> feats layout for stage 2)
    k_bn<<<Co1, 256, 0, stream>>>(pooled1, g0, be0, feats2, B, Co1, G1, 1);

    // ---- stage 2 (xyz = lcx1, feats = feats2) ----
    // FPS on an FPS-ordered prefix set is the identity permutation (prefix-nesting).
    // 7. kNN + identity gather + fused std partials
    k_knn_t<8><<<B*G2, 256, 0, stream>>>(lcx1, feats2, (const int*)nullptr,
                                         lcx2, lcf2, ki2, part, B, N2, G2, C1, 1);
    // 8. partials -> acc[4..7]
    k_reduce<<<1, 1024, 0, stream>>>(part, acc + 4, B*G2);
    // 9. feature + pool
    {
        size_t shf = (size_t)(KNB*7 + KNB*3 + KNB + 2*KNB*C1) * 4;
        k_feature<<<B*G2, 256, shf, stream>>>(lcx1, feats2, lcx2, lcf2, ki2, B1, acc + 4, pooled2,
                                              B, N2, G2, C1,
                                              (double)B*G2*KNB*C1, (double)B*G2*KNB*3);
    }
    // 10. BN + GELU -> final output
    k_bn<<<Co2, 256, 0, stream>>>(pooled2, g1, be1, out, B, Co2, G2, 0);
}